// Round 1
// 577.129 us; speedup vs baseline: 1.0989x; 1.0989x over previous
//
#include <hip/hip_runtime.h>
#include <cstdint>
#include <cstddef>

#define N_USER 100000
#define N_ITEM 50000
#define CDIM   128
#define NEDGE  600000
#define N_SEG  (N_ITEM + N_USER)          // item segments first, then user
#define NB_SCAN ((N_SEG + 255) / 256)     // 586 scan blocks

// XCD-sliced fill parameters
#define FILL_EPB 2048                           // edges per block-chunk
#define FILL_NCHUNK ((NEDGE + FILL_EPB - 1) / FILL_EPB)   // 293
#define SLICE_DIV ((N_SEG + 7) / 8)             // 18750 segments per slice

typedef __bf16 bf16_t;
typedef bf16_t bfvec8 __attribute__((ext_vector_type(8)));
typedef bf16_t bfvec4 __attribute__((ext_vector_type(4)));
typedef float  f32x4  __attribute__((ext_vector_type(4)));

// LDS row stride for 128-wide bf16 tiles: 136 elems = 272 B. 16B-aligned rows,
// fragment reads land 2 lanes/bank (free, m136). Proven R3..R7.
#define LDW 136

// Stage a 128x128 fp32 weight (row-major [k][n]) into LDS as bf16 Wt[n][k].
static __device__ inline void stage_w(bf16_t* Wt, const float* __restrict__ W, int tid) {
    const f32x4* W4 = reinterpret_cast<const f32x4*>(W);
    #pragma unroll
    for (int i = 0; i < 16; ++i) {
        int cidx = i * 256 + tid;
        int base = cidx * 4;
        int k  = base >> 7;
        int n0 = base & 127;
        f32x4 v = W4[cidx];
        #pragma unroll
        for (int j = 0; j < 4; ++j) Wt[(n0 + j) * LDW + k] = (bf16_t)v[j];
    }
}

// ---------------------------------------------------------------------------
// Init GEMM: Y[M,128] = X@W + bias, X fp32 (raw inputs), Y bf16 (ws).
// MFMA 16x16x32_bf16: A[m=lane&15][k=quad*8+j], B[k][n=lane&15],
// D reg r -> row=quad*4+r, col=lane&15  (proven layouts).
// ---------------------------------------------------------------------------
__global__ __launch_bounds__(256) void gemm_init(
    const float* __restrict__ X,
    const float* __restrict__ W,
    const float* __restrict__ B,
    bf16_t* __restrict__ Y, int M)
{
    __shared__ __align__(16) bf16_t Wt[128 * LDW];
    const int tid = threadIdx.x;
    stage_w(Wt, W, tid);
    __syncthreads();

    const int wave = tid >> 6, lane = tid & 63;
    const int quad = lane >> 4, ln16 = lane & 15;

    #pragma unroll
    for (int s = 0; s < 2; ++s) {
        int row0 = blockIdx.x * 128 + s * 64 + wave * 16;
        int arow = row0 + ln16;
        int arow_c = arow < M ? arow : 0;

        bfvec8 a[4];
        const float* xp = X + (size_t)arow_c * CDIM + quad * 8;
        #pragma unroll
        for (int kc = 0; kc < 4; ++kc) {
            f32x4 lo = *reinterpret_cast<const f32x4*>(xp + kc * 32);
            f32x4 hi = *reinterpret_cast<const f32x4*>(xp + kc * 32 + 4);
            #pragma unroll
            for (int j = 0; j < 4; ++j) {
                a[kc][j]     = (bf16_t)lo[j];
                a[kc][j + 4] = (bf16_t)hi[j];
            }
        }

        f32x4 acc[8];
        #pragma unroll
        for (int t = 0; t < 8; ++t) acc[t] = (f32x4){0.f, 0.f, 0.f, 0.f};
        #pragma unroll
        for (int t = 0; t < 8; ++t) {
            const bf16_t* wp = &Wt[(t * 16 + ln16) * LDW + quad * 8];
            #pragma unroll
            for (int kc = 0; kc < 4; ++kc) {
                bfvec8 b = *reinterpret_cast<const bfvec8*>(wp + kc * 32);
                acc[t] = __builtin_amdgcn_mfma_f32_16x16x32_bf16(a[kc], b, acc[t], 0, 0, 0);
            }
        }

        if (row0 < M) {
            #pragma unroll
            for (int t = 0; t < 8; ++t) {
                int col = t * 16 + ln16;
                float bias = B[col];
                #pragma unroll
                for (int r = 0; r < 4; ++r) {
                    int row = row0 + quad * 4 + r;
                    if (row < M) Y[(size_t)row * CDIM + col] = (bf16_t)(acc[t][r] + bias);
                }
            }
        }
    }
}

// ---------------------------------------------------------------------------
// CSR build pieces
// ---------------------------------------------------------------------------
__global__ __launch_bounds__(256) void zero_i32(int* __restrict__ p, int n)
{
    int i = blockIdx.x * 256 + threadIdx.x;
    if (i < n) p[i] = 0;
}

// Histogram + rank capture: atomicAdd's return value IS this edge's rank
// within its destination segment. One coalesced 8B store per edge pair.
__global__ __launch_bounds__(256) void hist_rank(
    const int* __restrict__ edge_ui, const int* __restrict__ edge_iu,
    int* __restrict__ deg, int2* __restrict__ rank2)
{
    int i = blockIdx.x * 256 + threadIdx.x;
    if (i >= NEDGE) return;
    int r0 = atomicAdd(&deg[edge_ui[NEDGE + i]], 1);
    int r1 = atomicAdd(&deg[N_ITEM + edge_iu[NEDGE + i]], 1);
    rank2[i] = make_int2(r0, r1);
}

__global__ __launch_bounds__(256) void block_scan(
    int* __restrict__ off, int* __restrict__ bsum, int n)
{
    __shared__ int sh[256];
    int tid = threadIdx.x;
    int i = blockIdx.x * 256 + tid;
    int v = (i < n) ? off[i] : 0;
    sh[tid] = v;
    __syncthreads();
    #pragma unroll
    for (int d = 1; d < 256; d <<= 1) {
        int t = (tid >= d) ? sh[tid - d] : 0;
        __syncthreads();
        sh[tid] += t;
        __syncthreads();
    }
    if (i < n) off[i] = sh[tid] - v;
    if (tid == 255) bsum[blockIdx.x] = sh[255];
}

__global__ __launch_bounds__(1024) void scan_bsums(int* __restrict__ bsum)
{
    __shared__ int sh[1024];
    int tid = threadIdx.x;
    int v = (tid < NB_SCAN) ? bsum[tid] : 0;
    sh[tid] = v;
    __syncthreads();
    #pragma unroll
    for (int d = 1; d < 1024; d <<= 1) {
        int t = (tid >= d) ? sh[tid - d] : 0;
        __syncthreads();
        sh[tid] += t;
        __syncthreads();
    }
    if (tid < NB_SCAN) bsum[tid] = sh[tid] - v;
    if (tid == 1023) bsum[NB_SCAN] = sh[1023];
}

__global__ __launch_bounds__(256) void add_offsets(
    int* __restrict__ off, const int* __restrict__ bsum, int n)
{
    int i = blockIdx.x * 256 + threadIdx.x;
    if (i < n) off[i] += bsum[i >> 8];
    else if (i == n) off[n] = bsum[NB_SCAN];
}

// ---------------------------------------------------------------------------
// Atomic-free, XCD-sliced CSR fill. slot = off[seg] + rank (rank captured in
// hist_rank). Segment space [0,150000) is cut into 8 contiguous slices of
// 18750 segments (<=900KB of srcbuf each, fits one XCD's 4MB L2). Block b
// processes edge-chunk b>>3 and writes only slice b&7; with round-robin
// blockIdx->XCD dispatch, all writers of a srcbuf line share one XCD -> L2
// write-combines the 16 slots/line instead of 16 partial-line drains to the
// coherence point. Correctness does NOT depend on the XCD mapping.
// ---------------------------------------------------------------------------
__global__ __launch_bounds__(256) void fill_sliced(
    const int* __restrict__ edge_ui, const int* __restrict__ edge_iu,
    const int* __restrict__ off, const int2* __restrict__ rank2,
    int* __restrict__ srcbuf)
{
    const int r = blockIdx.x & 7;
    const int chunk = blockIdx.x >> 3;
    const int base = chunk * FILL_EPB + threadIdx.x;
    #pragma unroll
    for (int j = 0; j < FILL_EPB / 256; ++j) {
        int i = base + j * 256;
        if (i < NEDGE) {
            int d0 = edge_ui[NEDGE + i];            // item dst; seg = d0
            int d1 = edge_iu[NEDGE + i] + N_ITEM;   // user dst; seg index
            int2 rk = rank2[i];
            if (d0 / SLICE_DIV == r)
                srcbuf[off[d0] + rk.x] = edge_ui[i];
            if (d1 / SLICE_DIV == r)
                srcbuf[off[d1] + rk.y] = edge_iu[i];
        }
    }
}

// ---------------------------------------------------------------------------
// Gather + GIN combine, bf16 features, fp32 accumulate. One wave per dst
// node; lane holds bfvec4 (8 B, 32 lanes/row = 256 B); half-waves alternate
// neighbors, combined via lane^32 shuffle. out = bf16((1+eps)*x + sum F).
// ---------------------------------------------------------------------------
__global__ __launch_bounds__(256) void gather_both(
    const bf16_t* __restrict__ xu, const bf16_t* __restrict__ xi,
    const float* __restrict__ eps2,            // eps + 2*l: [item, user]
    const int* __restrict__ off_all, const int* __restrict__ srcbuf,
    bf16_t* __restrict__ ti, bf16_t* __restrict__ tu)
{
    const int gBI = (N_ITEM + 3) / 4;
    int b = blockIdx.x;
    bool isItem = b < gBI;
    int wave = threadIdx.x >> 6;
    int node = (isItem ? b : b - gBI) * 4 + wave;
    int n = isItem ? N_ITEM : N_USER;
    if (node >= n) return;

    const bfvec4* F = reinterpret_cast<const bfvec4*>(isItem ? xu : xi);
    const bfvec4* X = reinterpret_cast<const bfvec4*>(isItem ? xi : xu);
    const int* off = isItem ? off_all : off_all + N_ITEM;
    bfvec4* out = reinterpret_cast<bfvec4*>(isItem ? ti : tu);
    float s = 1.f + (isItem ? eps2[0] : eps2[1]);

    int l32  = threadIdx.x & 31;
    int half = (threadIdx.x >> 5) & 1;
    int start = off[node], end = off[node + 1];

    f32x4 acc = (f32x4){0.f, 0.f, 0.f, 0.f};
    int e = start + half;
    for (; e + 6 < end; e += 8) {
        bfvec4 v0 = F[(size_t)srcbuf[e]     * 32 + l32];
        bfvec4 v1 = F[(size_t)srcbuf[e + 2] * 32 + l32];
        bfvec4 v2 = F[(size_t)srcbuf[e + 4] * 32 + l32];
        bfvec4 v3 = F[(size_t)srcbuf[e + 6] * 32 + l32];
        #pragma unroll
        for (int j = 0; j < 4; ++j)
            acc[j] += ((float)v0[j] + (float)v1[j]) + ((float)v2[j] + (float)v3[j]);
    }
    for (; e + 2 < end; e += 4) {
        bfvec4 v0 = F[(size_t)srcbuf[e]     * 32 + l32];
        bfvec4 v1 = F[(size_t)srcbuf[e + 2] * 32 + l32];
        #pragma unroll
        for (int j = 0; j < 4; ++j) acc[j] += (float)v0[j] + (float)v1[j];
    }
    for (; e < end; e += 2) {
        bfvec4 v = F[(size_t)srcbuf[e] * 32 + l32];
        #pragma unroll
        for (int j = 0; j < 4; ++j) acc[j] += (float)v[j];
    }
    #pragma unroll
    for (int j = 0; j < 4; ++j) acc[j] += __shfl_xor(acc[j], 32, 64);

    if (half == 0) {
        bfvec4 xv = X[(size_t)node * 32 + l32];
        bfvec4 o;
        #pragma unroll
        for (int j = 0; j < 4; ++j) o[j] = (bf16_t)(s * (float)xv[j] + acc[j]);
        out[(size_t)node * 32 + l32] = o;
    }
}

// ---------------------------------------------------------------------------
// Fused MLP (linear->ReLU x2) + LayerNorm + ReLU, both node types,
// 128 rows/block. A loaded directly as bf16 (no cvt). H1 round-trips
// through At (bf16, LDW stride). ReLU after BOTH linears (R6 fix), then LN.
// Output: bf16 to ws (l=0) or fp32 to d_out (l=1), runtime flag.
// LDS 69,632 B -> 2 blocks/CU.
// ---------------------------------------------------------------------------
__global__ __launch_bounds__(256) void mlp_ln_both(
    const bf16_t* __restrict__ ti, const bf16_t* __restrict__ tu,
    const float* __restrict__ mlpW,   // mlp_W + l*4*16384
    const float* __restrict__ mlpb,   // mlp_b + l*4*128
    const float* __restrict__ lng,    // ln_g + l*2*128
    const float* __restrict__ lnb,    // ln_b + l*2*128
    bf16_t* __restrict__ xib, bf16_t* __restrict__ xub,   // bf16 outs (l=0)
    float* __restrict__ xif, float* __restrict__ xuf,     // fp32 outs (l=1)
    int f32out)
{
    __shared__ __align__(16) bf16_t Wt[128 * LDW];
    __shared__ __align__(16) bf16_t At[128 * LDW];

    const int gBI = (N_ITEM + 127) / 128;
    int b = blockIdx.x;
    bool isItem = b < gBI;
    const bf16_t* X = isItem ? ti : tu;
    bf16_t* Yb      = isItem ? xib : xub;
    float*  Yf      = isItem ? xif : xuf;
    int M  = isItem ? N_ITEM : N_USER;
    int bx = isItem ? b : b - gBI;
    // edge type 0 = (user->item) => item dst; 1 = (item->user) => user dst
    const float* W1 = mlpW + (isItem ? 0 : 2) * 16384;
    const float* W2 = W1 + 16384;
    const float* B1 = mlpb + (isItem ? 0 : 2) * 128;
    const float* B2 = B1 + 128;
    // node type 0 = user, 1 = item
    const float* G  = lng + (isItem ? 128 : 0);
    const float* Bb = lnb + (isItem ? 128 : 0);

    const int tid = threadIdx.x;
    stage_w(Wt, W1, tid);
    __syncthreads();

    const int wave = tid >> 6, lane = tid & 63;
    const int quad = lane >> 4, ln16 = lane & 15;
    const int rowBase = bx * 128;

    // ---- GEMM1: X -> relu(X@W1+b1) -> At[row][k] ----
    #pragma unroll
    for (int s = 0; s < 2; ++s) {
        int row0l = s * 64 + wave * 16;
        int arow = rowBase + row0l + ln16;
        int arow_c = arow < M ? arow : 0;

        bfvec8 a[4];
        const bf16_t* xp = X + (size_t)arow_c * CDIM + quad * 8;
        #pragma unroll
        for (int kc = 0; kc < 4; ++kc)
            a[kc] = *reinterpret_cast<const bfvec8*>(xp + kc * 32);

        f32x4 acc[8];
        #pragma unroll
        for (int t = 0; t < 8; ++t) acc[t] = (f32x4){0.f, 0.f, 0.f, 0.f};
        #pragma unroll
        for (int t = 0; t < 8; ++t) {
            const bf16_t* wp = &Wt[(t * 16 + ln16) * LDW + quad * 8];
            #pragma unroll
            for (int kc = 0; kc < 4; ++kc) {
                bfvec8 bv = *reinterpret_cast<const bfvec8*>(wp + kc * 32);
                acc[t] = __builtin_amdgcn_mfma_f32_16x16x32_bf16(a[kc], bv, acc[t], 0, 0, 0);
            }
        }

        #pragma unroll
        for (int t = 0; t < 8; ++t) {
            int col = t * 16 + ln16;
            float bias = B1[col];
            #pragma unroll
            for (int r = 0; r < 4; ++r) {
                float v = acc[t][r] + bias;
                v = v > 0.f ? v : 0.f;
                At[(row0l + quad * 4 + r) * LDW + col] = (bf16_t)v;
            }
        }
    }
    __syncthreads();
    stage_w(Wt, W2, tid);      // overwrite W1; all GEMM1 reads complete
    __syncthreads();

    // ---- GEMM2 from At + bias + ReLU + LayerNorm + ReLU -> Y ----
    #pragma unroll
    for (int s = 0; s < 2; ++s) {
        int row0l = s * 64 + wave * 16;
        int ml = row0l + ln16;

        bfvec8 a[4];
        #pragma unroll
        for (int kc = 0; kc < 4; ++kc)
            a[kc] = *reinterpret_cast<const bfvec8*>(&At[ml * LDW + kc * 32 + quad * 8]);

        f32x4 acc[8];
        #pragma unroll
        for (int t = 0; t < 8; ++t) acc[t] = (f32x4){0.f, 0.f, 0.f, 0.f};
        #pragma unroll
        for (int t = 0; t < 8; ++t) {
            const bf16_t* wp = &Wt[(t * 16 + ln16) * LDW + quad * 8];
            #pragma unroll
            for (int kc = 0; kc < 4; ++kc) {
                bfvec8 bv = *reinterpret_cast<const bfvec8*>(wp + kc * 32);
                acc[t] = __builtin_amdgcn_mfma_f32_16x16x32_bf16(a[kc], bv, acc[t], 0, 0, 0);
            }
        }

        float gA[8], bA[8];
        #pragma unroll
        for (int t = 0; t < 8; ++t) {
            int col = t * 16 + ln16;
            float b2 = B2[col];
            #pragma unroll
            for (int r = 0; r < 4; ++r) {
                float v = acc[t][r] + b2;
                acc[t][r] = v > 0.f ? v : 0.f;       // ReLU after 2nd linear (R6 fix)
            }
            gA[t] = G[col]; bA[t] = Bb[col];
        }

        // LN: row (quad*4+r) spans 8 regs x the 16 lanes of this quad
        #pragma unroll
        for (int r = 0; r < 4; ++r) {
            float sm = 0.f;
            #pragma unroll
            for (int t = 0; t < 8; ++t) sm += acc[t][r];
            #pragma unroll
            for (int m = 8; m >= 1; m >>= 1) sm += __shfl_xor(sm, m, 16);
            float mean = sm * (1.f / 128.f);
            float sq = 0.f;
            #pragma unroll
            for (int t = 0; t < 8; ++t) { float d = acc[t][r] - mean; sq += d * d; }
            #pragma unroll
            for (int m = 8; m >= 1; m >>= 1) sq += __shfl_xor(sq, m, 16);
            float rs = rsqrtf(sq * (1.f / 128.f) + 1e-5f);

            int row = rowBase + row0l + quad * 4 + r;
            if (row < M) {
                if (f32out) {
                    #pragma unroll
                    for (int t = 0; t < 8; ++t) {
                        float y = (acc[t][r] - mean) * rs * gA[t] + bA[t];
                        y = y > 0.f ? y : 0.f;
                        Yf[(size_t)row * CDIM + t * 16 + ln16] = y;
                    }
                } else {
                    #pragma unroll
                    for (int t = 0; t < 8; ++t) {
                        float y = (acc[t][r] - mean) * rs * gA[t] + bA[t];
                        y = y > 0.f ? y : 0.f;
                        Yb[(size_t)row * CDIM + t * 16 + ln16] = (bf16_t)y;
                    }
                }
            }
        }
    }
}

// ---------------------------------------------------------------------------
extern "C" void kernel_launch(void* const* d_in, const int* in_sizes, int n_in,
                              void* d_out, int out_size, void* d_ws, size_t ws_size,
                              hipStream_t stream)
{
    const float* x_user = (const float*)d_in[0];
    const float* x_item = (const float*)d_in[1];
    const float* W_init = (const float*)d_in[2];
    const float* b_init = (const float*)d_in[3];
    const float* mlp_W  = (const float*)d_in[4];
    const float* mlp_b  = (const float*)d_in[5];
    const float* eps    = (const float*)d_in[6];
    const float* ln_g   = (const float*)d_in[7];
    const float* ln_b   = (const float*)d_in[8];
    const int* edge_ui  = (const int*)d_in[9];
    const int* edge_iu  = (const int*)d_in[10];

    // final fp32 outputs
    float* xuf = (float*)d_out;                     // [N_USER,128]
    float* xif = xuf + (size_t)N_USER * CDIM;       // [N_ITEM,128]

    // ws: bf16 activations + CSR
    char* w = (char*)d_ws;
    bf16_t* xub = (bf16_t*)w;                                  // 25.6 MB
    bf16_t* xib = xub + (size_t)N_USER * CDIM;                 // 12.8 MB
    bf16_t* tub = xib + (size_t)N_ITEM * CDIM;                 // 25.6 MB
    bf16_t* tib = tub + (size_t)N_USER * CDIM;                 // 12.8 MB
    int* off_all = (int*)(tib + (size_t)N_ITEM * CDIM);        // N_SEG+1
    int* bsum    = off_all + (N_SEG + 4);
    int* srcbuf  = bsum + (NB_SCAN + 2);                       // 2*NEDGE

    // rank2 aliases tub: live only hist_rank -> fill_sliced, before any
    // gather_both writes tub. 4.8 MB < 25.6 MB region. 8B-aligned.
    int2* rank2 = (int2*)tub;

    const int gU = (N_USER + 127) / 128;            // 782
    const int gI = (N_ITEM + 127) / 128;            // 391
    const int gSeg = (N_SEG + 256) / 256;
    const int gE = (NEDGE + 255) / 256;             // 2344
    const int gGather = (N_ITEM + 3) / 4 + (N_USER + 3) / 4;

    // CSR prep
    zero_i32<<<(N_SEG + 255) / 256, 256, 0, stream>>>(off_all, N_SEG);
    hist_rank<<<gE, 256, 0, stream>>>(edge_ui, edge_iu, off_all, rank2);
    block_scan<<<NB_SCAN, 256, 0, stream>>>(off_all, bsum, N_SEG);
    scan_bsums<<<1, 1024, 0, stream>>>(bsum);
    add_offsets<<<gSeg, 256, 0, stream>>>(off_all, bsum, N_SEG);
    fill_sliced<<<FILL_NCHUNK * 8, 256, 0, stream>>>(edge_ui, edge_iu, off_all, rank2, srcbuf);

    // initial projection -> bf16 ws
    gemm_init<<<gU, 256, 0, stream>>>(x_user, W_init,         b_init,       xub, N_USER);
    gemm_init<<<gI, 256, 0, stream>>>(x_item, W_init + 16384, b_init + 128, xib, N_ITEM);

    for (int l = 0; l < 2; ++l) {
        gather_both<<<gGather, 256, 0, stream>>>(
            xub, xib, eps + 2 * l, off_all, srcbuf, tib, tub);
        mlp_ln_both<<<gI + gU, 256, 0, stream>>>(
            tib, tub, mlp_W + (size_t)l * 4 * 16384, mlp_b + l * 4 * 128,
            ln_g + l * 2 * 128, ln_b + l * 2 * 128,
            xib, xub, xif, xuf, (l == 1) ? 1 : 0);
    }
}

// Round 2
// 472.088 us; speedup vs baseline: 1.3434x; 1.2225x over previous
//
#include <hip/hip_runtime.h>
#include <cstdint>
#include <cstddef>

#define N_USER 100000
#define N_ITEM 50000
#define CDIM   128
#define NEDGE  600000
#define N_SEG  (N_ITEM + N_USER)          // item segments first, then user
#define NB_SCAN ((N_SEG + 255) / 256)     // 586 scan blocks

// XCD-sliced fill parameters
#define FILL_EPB 2048                           // edges per block-chunk
#define FILL_NCHUNK ((NEDGE + FILL_EPB - 1) / FILL_EPB)   // 293
#define SLICE_DIV ((N_SEG + 7) / 8)             // 18750 segments per slice

typedef __bf16 bf16_t;
typedef bf16_t bfvec8 __attribute__((ext_vector_type(8)));
typedef bf16_t bfvec4 __attribute__((ext_vector_type(4)));
typedef float  f32x4  __attribute__((ext_vector_type(4)));

// LDS row stride for 128-wide bf16 tiles: 136 elems = 272 B (16B-aligned rows).
#define LDW 136

// ---------------------------------------------------------------------------
// One-time: transpose+cvt all 10 weight matrices (W_init[2], mlp_W[8]) from
// fp32 [k][n] to bf16 [n][k] in ws. Kills the 16-way-conflicted in-LDS
// transpose that every GEMM block used to pay. Reads are L2-cached (640KB).
// ---------------------------------------------------------------------------
__global__ __launch_bounds__(256) void prep_weights(
    const float* __restrict__ W_init, const float* __restrict__ mlp_W,
    bf16_t* __restrict__ wtg)
{
    int m  = blockIdx.x >> 6;            // 10 matrices x 64 blocks
    int it = blockIdx.x & 63;
    const float* src = (m < 2) ? (W_init + (size_t)m * 16384)
                               : (mlp_W + (size_t)(m - 2) * 16384);
    int e = it * 256 + threadIdx.x;      // e = n*128 + k
    int n = e >> 7, k = e & 127;
    wtg[(size_t)m * 16384 + e] = (bf16_t)src[k * 128 + n];
}

// Vectorized stage: pre-transposed bf16 weight [n][k] -> LDS padded rows.
// 16B loads + 16B LDS writes, ~bandwidth-floor banks (vs 16-way scalar before).
template <int NT>
static __device__ inline void stage_wbf(bf16_t* Wt, const bf16_t* __restrict__ Wg, int tid) {
    #pragma unroll
    for (int c = tid; c < 2048; c += NT) {
        int n = c >> 4, koff = (c & 15) * 8;
        *reinterpret_cast<bfvec8*>(&Wt[n * LDW + koff]) =
            *reinterpret_cast<const bfvec8*>(&Wg[n * 128 + koff]);
    }
}

// ---------------------------------------------------------------------------
// Init GEMM, swapped operands: D = W^T-frag (A) x X-row-frag (B) = (X@W)^T
// per-tile. MFMA 16x16x32_bf16 layouts (proven): A[m=lane&15][k=quad*8+j],
// B[k][n=lane&15], D reg r -> m=quad*4+r, n=lane&15. With the swap:
// m = output COLUMN, n = output ROW -> lane holds 4 consecutive output cols
// of its own row => 8B vector stores. 512 thr, wave w owns rows w*16..+15.
// ---------------------------------------------------------------------------
__global__ __launch_bounds__(512) void gemm_init(
    const float* __restrict__ X,
    const bf16_t* __restrict__ Wg,     // pre-transposed bf16 [n][k]
    const float* __restrict__ B,
    bf16_t* __restrict__ Y, int M)
{
    __shared__ __align__(16) bf16_t Wt[128 * LDW];
    const int tid = threadIdx.x;
    stage_wbf<512>(Wt, Wg, tid);
    __syncthreads();

    const int wave = tid >> 6, lane = tid & 63;
    const int quad = lane >> 4, ln16 = lane & 15;
    const int row_l = wave * 16 + ln16;
    const int rowg = blockIdx.x * 128 + row_l;
    const int rowc = rowg < M ? rowg : 0;

    // B-fragment: this lane's row of X (fp32 -> bf16 in regs)
    bfvec8 xb[4];
    const float* xp = X + (size_t)rowc * CDIM + quad * 8;
    #pragma unroll
    for (int kc = 0; kc < 4; ++kc) {
        f32x4 lo = *reinterpret_cast<const f32x4*>(xp + kc * 32);
        f32x4 hi = *reinterpret_cast<const f32x4*>(xp + kc * 32 + 4);
        #pragma unroll
        for (int j = 0; j < 4; ++j) {
            xb[kc][j]     = (bf16_t)lo[j];
            xb[kc][j + 4] = (bf16_t)hi[j];
        }
    }

    f32x4 acc[8];
    #pragma unroll
    for (int t = 0; t < 8; ++t) acc[t] = (f32x4){0.f, 0.f, 0.f, 0.f};
    #pragma unroll
    for (int t = 0; t < 8; ++t) {
        const bf16_t* wp = &Wt[(t * 16 + ln16) * LDW + quad * 8];
        #pragma unroll
        for (int kc = 0; kc < 4; ++kc) {
            bfvec8 wv = *reinterpret_cast<const bfvec8*>(wp + kc * 32);
            acc[t] = __builtin_amdgcn_mfma_f32_16x16x32_bf16(wv, xb[kc], acc[t], 0, 0, 0);
        }
    }

    if (rowg < M) {
        #pragma unroll
        for (int t = 0; t < 8; ++t) {
            f32x4 bv = *reinterpret_cast<const f32x4*>(&B[t * 16 + quad * 4]);
            bfvec4 o;
            #pragma unroll
            for (int r = 0; r < 4; ++r) o[r] = (bf16_t)(acc[t][r] + bv[r]);
            *reinterpret_cast<bfvec4*>(&Y[(size_t)rowg * CDIM + t * 16 + quad * 4]) = o;
        }
    }
}

// ---------------------------------------------------------------------------
// CSR build pieces
// ---------------------------------------------------------------------------
__global__ __launch_bounds__(256) void zero_i32(int* __restrict__ p, int n)
{
    int i = blockIdx.x * 256 + threadIdx.x;
    if (i < n) p[i] = 0;
}

// Histogram + rank capture: atomicAdd's return value IS this edge's rank
// within its destination segment. One coalesced 8B store per edge pair.
__global__ __launch_bounds__(256) void hist_rank(
    const int* __restrict__ edge_ui, const int* __restrict__ edge_iu,
    int* __restrict__ deg, int2* __restrict__ rank2)
{
    int i = blockIdx.x * 256 + threadIdx.x;
    if (i >= NEDGE) return;
    int r0 = atomicAdd(&deg[edge_ui[NEDGE + i]], 1);
    int r1 = atomicAdd(&deg[N_ITEM + edge_iu[NEDGE + i]], 1);
    rank2[i] = make_int2(r0, r1);
}

__global__ __launch_bounds__(256) void block_scan(
    int* __restrict__ off, int* __restrict__ bsum, int n)
{
    __shared__ int sh[256];
    int tid = threadIdx.x;
    int i = blockIdx.x * 256 + tid;
    int v = (i < n) ? off[i] : 0;
    sh[tid] = v;
    __syncthreads();
    #pragma unroll
    for (int d = 1; d < 256; d <<= 1) {
        int t = (tid >= d) ? sh[tid - d] : 0;
        __syncthreads();
        sh[tid] += t;
        __syncthreads();
    }
    if (i < n) off[i] = sh[tid] - v;
    if (tid == 255) bsum[blockIdx.x] = sh[255];
}

__global__ __launch_bounds__(1024) void scan_bsums(int* __restrict__ bsum)
{
    __shared__ int sh[1024];
    int tid = threadIdx.x;
    int v = (tid < NB_SCAN) ? bsum[tid] : 0;
    sh[tid] = v;
    __syncthreads();
    #pragma unroll
    for (int d = 1; d < 1024; d <<= 1) {
        int t = (tid >= d) ? sh[tid - d] : 0;
        __syncthreads();
        sh[tid] += t;
        __syncthreads();
    }
    if (tid < NB_SCAN) bsum[tid] = sh[tid] - v;
    if (tid == 1023) bsum[NB_SCAN] = sh[1023];
}

__global__ __launch_bounds__(256) void add_offsets(
    int* __restrict__ off, const int* __restrict__ bsum, int n)
{
    int i = blockIdx.x * 256 + threadIdx.x;
    if (i < n) off[i] += bsum[i >> 8];
    else if (i == n) off[n] = bsum[NB_SCAN];
}

// ---------------------------------------------------------------------------
// Atomic-free, XCD-sliced CSR fill. slot = off[seg] + rank (from hist_rank).
// Block b processes edge-chunk b>>3 and writes only segment-slice b&7; with
// round-robin blockIdx->XCD dispatch all writers of a srcbuf line share one
// XCD's L2 -> write-combining instead of 16 partial-line drains.
// ---------------------------------------------------------------------------
__global__ __launch_bounds__(256) void fill_sliced(
    const int* __restrict__ edge_ui, const int* __restrict__ edge_iu,
    const int* __restrict__ off, const int2* __restrict__ rank2,
    int* __restrict__ srcbuf)
{
    const int r = blockIdx.x & 7;
    const int chunk = blockIdx.x >> 3;
    const int base = chunk * FILL_EPB + threadIdx.x;
    #pragma unroll
    for (int j = 0; j < FILL_EPB / 256; ++j) {
        int i = base + j * 256;
        if (i < NEDGE) {
            int d0 = edge_ui[NEDGE + i];            // item dst; seg = d0
            int d1 = edge_iu[NEDGE + i] + N_ITEM;   // user dst; seg index
            int2 rk = rank2[i];
            if (d0 / SLICE_DIV == r)
                srcbuf[off[d0] + rk.x] = edge_ui[i];
            if (d1 / SLICE_DIV == r)
                srcbuf[off[d1] + rk.y] = edge_iu[i];
        }
    }
}

// ---------------------------------------------------------------------------
// Gather + GIN combine, bf16 features, fp32 accumulate. One wave per dst
// node; lane holds bfvec4 (8 B, 32 lanes/row = 256 B); half-waves alternate
// neighbors, combined via lane^32 shuffle. out = bf16((1+eps)*x + sum F).
// ---------------------------------------------------------------------------
__global__ __launch_bounds__(256) void gather_both(
    const bf16_t* __restrict__ xu, const bf16_t* __restrict__ xi,
    const float* __restrict__ eps2,            // eps + 2*l: [item, user]
    const int* __restrict__ off_all, const int* __restrict__ srcbuf,
    bf16_t* __restrict__ ti, bf16_t* __restrict__ tu)
{
    const int gBI = (N_ITEM + 3) / 4;
    int b = blockIdx.x;
    bool isItem = b < gBI;
    int wave = threadIdx.x >> 6;
    int node = (isItem ? b : b - gBI) * 4 + wave;
    int n = isItem ? N_ITEM : N_USER;
    if (node >= n) return;

    const bfvec4* F = reinterpret_cast<const bfvec4*>(isItem ? xu : xi);
    const bfvec4* X = reinterpret_cast<const bfvec4*>(isItem ? xi : xu);
    const int* off = isItem ? off_all : off_all + N_ITEM;
    bfvec4* out = reinterpret_cast<bfvec4*>(isItem ? ti : tu);
    float s = 1.f + (isItem ? eps2[0] : eps2[1]);

    int l32  = threadIdx.x & 31;
    int half = (threadIdx.x >> 5) & 1;
    int start = off[node], end = off[node + 1];

    f32x4 acc = (f32x4){0.f, 0.f, 0.f, 0.f};
    int e = start + half;
    for (; e + 6 < end; e += 8) {
        bfvec4 v0 = F[(size_t)srcbuf[e]     * 32 + l32];
        bfvec4 v1 = F[(size_t)srcbuf[e + 2] * 32 + l32];
        bfvec4 v2 = F[(size_t)srcbuf[e + 4] * 32 + l32];
        bfvec4 v3 = F[(size_t)srcbuf[e + 6] * 32 + l32];
        #pragma unroll
        for (int j = 0; j < 4; ++j)
            acc[j] += ((float)v0[j] + (float)v1[j]) + ((float)v2[j] + (float)v3[j]);
    }
    for (; e + 2 < end; e += 4) {
        bfvec4 v0 = F[(size_t)srcbuf[e]     * 32 + l32];
        bfvec4 v1 = F[(size_t)srcbuf[e + 2] * 32 + l32];
        #pragma unroll
        for (int j = 0; j < 4; ++j) acc[j] += (float)v0[j] + (float)v1[j];
    }
    for (; e < end; e += 2) {
        bfvec4 v = F[(size_t)srcbuf[e] * 32 + l32];
        #pragma unroll
        for (int j = 0; j < 4; ++j) acc[j] += (float)v[j];
    }
    #pragma unroll
    for (int j = 0; j < 4; ++j) acc[j] += __shfl_xor(acc[j], 32, 64);

    if (half == 0) {
        bfvec4 xv = X[(size_t)node * 32 + l32];
        bfvec4 o;
        #pragma unroll
        for (int j = 0; j < 4; ++j) o[j] = (bf16_t)(s * (float)xv[j] + acc[j]);
        out[(size_t)node * 32 + l32] = o;
    }
}

// ---------------------------------------------------------------------------
// Fused MLP (linear->ReLU x2) + LayerNorm + ReLU, both node types, swapped
// MFMA operands: lane holds 4 consecutive OUTPUT COLS of its own row ->
// At round-trip and global stores are vector writes; LN needs only 2 quad
// shuffles. 512 thr (8 waves x 16 rows), weights pre-transposed bf16.
// LDS 69,632 B -> 2 blocks/CU -> 4 waves/SIMD.
// ---------------------------------------------------------------------------
__global__ __launch_bounds__(512) void mlp_ln_both(
    const bf16_t* __restrict__ ti, const bf16_t* __restrict__ tu,
    const bf16_t* __restrict__ wg,    // this layer: [itemW1, itemW2, userW1, userW2], bf16 [n][k]
    const float* __restrict__ mlpb,   // mlp_b + l*4*128
    const float* __restrict__ lng,    // ln_g + l*2*128
    const float* __restrict__ lnb,    // ln_b + l*2*128
    bf16_t* __restrict__ xib, bf16_t* __restrict__ xub,   // bf16 outs (l=0)
    float* __restrict__ xif, float* __restrict__ xuf,     // fp32 outs (l=1)
    int f32out)
{
    __shared__ __align__(16) bf16_t Wt[128 * LDW];
    __shared__ __align__(16) bf16_t At[128 * LDW];

    const int gBI = (N_ITEM + 127) / 128;
    int b = blockIdx.x;
    bool isItem = b < gBI;
    const bf16_t* X = isItem ? ti : tu;
    bf16_t* Yb      = isItem ? xib : xub;
    float*  Yf      = isItem ? xif : xuf;
    int M  = isItem ? N_ITEM : N_USER;
    int bx = isItem ? b : b - gBI;
    // edge type 0 = (user->item) => item dst; 1 = (item->user) => user dst
    const bf16_t* W1 = wg + (isItem ? 0 : 2) * 16384;
    const bf16_t* W2 = W1 + 16384;
    const float* B1 = mlpb + (isItem ? 0 : 2) * 128;
    const float* B2 = B1 + 128;
    // node type 0 = user, 1 = item
    const float* G  = lng + (isItem ? 128 : 0);
    const float* Bb = lnb + (isItem ? 128 : 0);

    const int tid = threadIdx.x;
    stage_wbf<512>(Wt, W1, tid);
    __syncthreads();

    const int wave = tid >> 6, lane = tid & 63;
    const int quad = lane >> 4, ln16 = lane & 15;
    const int row_l = wave * 16 + ln16;
    const int rowg = bx * 128 + row_l;
    const int rowc = rowg < M ? rowg : 0;

    // ---- GEMM1: relu(X@W1+b1) -> At[row][k] (vector 8B writes) ----
    bfvec8 xb[4];
    const bf16_t* xp = X + (size_t)rowc * CDIM + quad * 8;
    #pragma unroll
    for (int kc = 0; kc < 4; ++kc)
        xb[kc] = *reinterpret_cast<const bfvec8*>(xp + kc * 32);

    f32x4 acc[8];
    #pragma unroll
    for (int t = 0; t < 8; ++t) acc[t] = (f32x4){0.f, 0.f, 0.f, 0.f};
    #pragma unroll
    for (int t = 0; t < 8; ++t) {
        const bf16_t* wp = &Wt[(t * 16 + ln16) * LDW + quad * 8];
        #pragma unroll
        for (int kc = 0; kc < 4; ++kc) {
            bfvec8 wv = *reinterpret_cast<const bfvec8*>(wp + kc * 32);
            acc[t] = __builtin_amdgcn_mfma_f32_16x16x32_bf16(wv, xb[kc], acc[t], 0, 0, 0);
        }
    }

    #pragma unroll
    for (int t = 0; t < 8; ++t) {
        f32x4 bv = *reinterpret_cast<const f32x4*>(&B1[t * 16 + quad * 4]);
        bfvec4 o;
        #pragma unroll
        for (int r = 0; r < 4; ++r) {
            float v = acc[t][r] + bv[r];
            o[r] = (bf16_t)(v > 0.f ? v : 0.f);
        }
        *reinterpret_cast<bfvec4*>(&At[row_l * LDW + t * 16 + quad * 4]) = o;
    }
    __syncthreads();
    stage_wbf<512>(Wt, W2, tid);       // overwrite W1; all GEMM1 reads complete
    __syncthreads();

    // ---- GEMM2 from At + bias + ReLU + LayerNorm + ReLU -> Y ----
    bfvec8 hb[4];
    #pragma unroll
    for (int kc = 0; kc < 4; ++kc)
        hb[kc] = *reinterpret_cast<const bfvec8*>(&At[row_l * LDW + kc * 32 + quad * 8]);

    #pragma unroll
    for (int t = 0; t < 8; ++t) acc[t] = (f32x4){0.f, 0.f, 0.f, 0.f};
    #pragma unroll
    for (int t = 0; t < 8; ++t) {
        const bf16_t* wp = &Wt[(t * 16 + ln16) * LDW + quad * 8];
        #pragma unroll
        for (int kc = 0; kc < 4; ++kc) {
            bfvec8 wv = *reinterpret_cast<const bfvec8*>(wp + kc * 32);
            acc[t] = __builtin_amdgcn_mfma_f32_16x16x32_bf16(wv, hb[kc], acc[t], 0, 0, 0);
        }
    }

    #pragma unroll
    for (int t = 0; t < 8; ++t) {
        f32x4 bv = *reinterpret_cast<const f32x4*>(&B2[t * 16 + quad * 4]);
        #pragma unroll
        for (int r = 0; r < 4; ++r) {
            float v = acc[t][r] + bv[r];
            acc[t][r] = v > 0.f ? v : 0.f;     // ReLU after 2nd linear
        }
    }

    // LN over this lane's own row: 32 in-lane values + 2 quad shuffles
    float sm = 0.f;
    #pragma unroll
    for (int t = 0; t < 8; ++t)
        #pragma unroll
        for (int r = 0; r < 4; ++r) sm += acc[t][r];
    sm += __shfl_xor(sm, 16, 64);
    sm += __shfl_xor(sm, 32, 64);
    float mean = sm * (1.f / 128.f);
    float sq = 0.f;
    #pragma unroll
    for (int t = 0; t < 8; ++t)
        #pragma unroll
        for (int r = 0; r < 4; ++r) { float d = acc[t][r] - mean; sq += d * d; }
    sq += __shfl_xor(sq, 16, 64);
    sq += __shfl_xor(sq, 32, 64);
    float rs = rsqrtf(sq * (1.f / 128.f) + 1e-5f);

    if (rowg < M) {
        if (f32out) {
            #pragma unroll
            for (int t = 0; t < 8; ++t) {
                f32x4 g4 = *reinterpret_cast<const f32x4*>(&G[t * 16 + quad * 4]);
                f32x4 b4 = *reinterpret_cast<const f32x4*>(&Bb[t * 16 + quad * 4]);
                f32x4 y;
                #pragma unroll
                for (int r = 0; r < 4; ++r) {
                    float v = (acc[t][r] - mean) * rs * g4[r] + b4[r];
                    y[r] = v > 0.f ? v : 0.f;
                }
                *reinterpret_cast<f32x4*>(&Yf[(size_t)rowg * CDIM + t * 16 + quad * 4]) = y;
            }
        } else {
            #pragma unroll
            for (int t = 0; t < 8; ++t) {
                f32x4 g4 = *reinterpret_cast<const f32x4*>(&G[t * 16 + quad * 4]);
                f32x4 b4 = *reinterpret_cast<const f32x4*>(&Bb[t * 16 + quad * 4]);
                bfvec4 y;
                #pragma unroll
                for (int r = 0; r < 4; ++r) {
                    float v = (acc[t][r] - mean) * rs * g4[r] + b4[r];
                    y[r] = (bf16_t)(v > 0.f ? v : 0.f);
                }
                *reinterpret_cast<bfvec4*>(&Yb[(size_t)rowg * CDIM + t * 16 + quad * 4]) = y;
            }
        }
    }
}

// ---------------------------------------------------------------------------
extern "C" void kernel_launch(void* const* d_in, const int* in_sizes, int n_in,
                              void* d_out, int out_size, void* d_ws, size_t ws_size,
                              hipStream_t stream)
{
    const float* x_user = (const float*)d_in[0];
    const float* x_item = (const float*)d_in[1];
    const float* W_init = (const float*)d_in[2];
    const float* b_init = (const float*)d_in[3];
    const float* mlp_W  = (const float*)d_in[4];
    const float* mlp_b  = (const float*)d_in[5];
    const float* eps    = (const float*)d_in[6];
    const float* ln_g   = (const float*)d_in[7];
    const float* ln_b   = (const float*)d_in[8];
    const int* edge_ui  = (const int*)d_in[9];
    const int* edge_iu  = (const int*)d_in[10];

    // final fp32 outputs
    float* xuf = (float*)d_out;                     // [N_USER,128]
    float* xif = xuf + (size_t)N_USER * CDIM;       // [N_ITEM,128]

    // ws: bf16 activations + CSR + pre-transposed weights
    char* w = (char*)d_ws;
    bf16_t* xub = (bf16_t*)w;                                  // 25.6 MB
    bf16_t* xib = xub + (size_t)N_USER * CDIM;                 // 12.8 MB
    bf16_t* tub = xib + (size_t)N_ITEM * CDIM;                 // 25.6 MB
    bf16_t* tib = tub + (size_t)N_USER * CDIM;                 // 12.8 MB
    int* off_all = (int*)(tib + (size_t)N_ITEM * CDIM);        // N_SEG+1
    int* bsum    = off_all + (N_SEG + 4);
    int* srcbuf  = bsum + (NB_SCAN + 2);                       // 2*NEDGE
    bf16_t* wtg  = (bf16_t*)(srcbuf + 2 * NEDGE);              // 10*16384 bf16 (16B-aligned)

    // rank2 aliases tub: live only hist_rank -> fill_sliced, before any
    // gather_both writes tub. 4.8 MB < 25.6 MB region. 8B-aligned.
    int2* rank2 = (int2*)tub;

    const int gU = (N_USER + 127) / 128;            // 782
    const int gI = (N_ITEM + 127) / 128;            // 391
    const int gSeg = (N_SEG + 256) / 256;
    const int gE = (NEDGE + 255) / 256;             // 2344
    const int gGather = (N_ITEM + 3) / 4 + (N_USER + 3) / 4;

    // one-time weight transpose (needs only inputs)
    prep_weights<<<640, 256, 0, stream>>>(W_init, mlp_W, wtg);

    // CSR prep
    zero_i32<<<(N_SEG + 255) / 256, 256, 0, stream>>>(off_all, N_SEG);
    hist_rank<<<gE, 256, 0, stream>>>(edge_ui, edge_iu, off_all, rank2);
    block_scan<<<NB_SCAN, 256, 0, stream>>>(off_all, bsum, N_SEG);
    scan_bsums<<<1, 1024, 0, stream>>>(bsum);
    add_offsets<<<gSeg, 256, 0, stream>>>(off_all, bsum, N_SEG);
    fill_sliced<<<FILL_NCHUNK * 8, 256, 0, stream>>>(edge_ui, edge_iu, off_all, rank2, srcbuf);

    // initial projection -> bf16 ws
    gemm_init<<<gU, 512, 0, stream>>>(x_user, wtg,         b_init,       xub, N_USER);
    gemm_init<<<gI, 512, 0, stream>>>(x_item, wtg + 16384, b_init + 128, xib, N_ITEM);

    for (int l = 0; l < 2; ++l) {
        gather_both<<<gGather, 256, 0, stream>>>(
            xub, xib, eps + 2 * l, off_all, srcbuf, tib, tub);
        mlp_ln_both<<<gI + gU, 512, 0, stream>>>(
            tib, tub, wtg + (size_t)(2 + l * 4) * 16384, mlp_b + l * 4 * 128,
            ln_g + l * 2 * 128, ln_b + l * 2 * 128,
            xib, xub, xif, xuf, (l == 1) ? 1 : 0);
    }
}

// Round 3
// 467.653 us; speedup vs baseline: 1.3562x; 1.0095x over previous
//
#include <hip/hip_runtime.h>
#include <cstdint>
#include <cstddef>

#define N_USER 100000
#define N_ITEM 50000
#define CDIM   128
#define NEDGE  600000
#define N_SEG  (N_ITEM + N_USER)          // item segments first, then user
#define NB_SCAN ((N_SEG + 255) / 256)     // 586 scan blocks

// XCD-sliced fill parameters
#define FILL_EPB 2048                           // edges per block-chunk
#define FILL_NCHUNK ((NEDGE + FILL_EPB - 1) / FILL_EPB)   // 293
#define SLICE_DIV ((N_SEG + 7) / 8)             // 18750 segments per slice

typedef __bf16 bf16_t;
typedef bf16_t bfvec8 __attribute__((ext_vector_type(8)));
typedef bf16_t bfvec4 __attribute__((ext_vector_type(4)));
typedef float  f32x4  __attribute__((ext_vector_type(4)));

// LDS row stride for 128-wide bf16 tiles: 136 elems = 272 B (16B-aligned rows).
#define LDW 136

// ---------------------------------------------------------------------------
// One-time: transpose+cvt all 10 weight matrices (W_init[2], mlp_W[8]) from
// fp32 [k][n] to bf16 [n][k] in ws. Kills the 16-way-conflicted in-LDS
// transpose that every GEMM block used to pay. Reads are L2-cached (640KB).
// ---------------------------------------------------------------------------
__global__ __launch_bounds__(256) void prep_weights(
    const float* __restrict__ W_init, const float* __restrict__ mlp_W,
    bf16_t* __restrict__ wtg)
{
    int m  = blockIdx.x >> 6;            // 10 matrices x 64 blocks
    int it = blockIdx.x & 63;
    const float* src = (m < 2) ? (W_init + (size_t)m * 16384)
                               : (mlp_W + (size_t)(m - 2) * 16384);
    int e = it * 256 + threadIdx.x;      // e = n*128 + k
    int n = e >> 7, k = e & 127;
    wtg[(size_t)m * 16384 + e] = (bf16_t)src[k * 128 + n];
}

// Vectorized stage: pre-transposed bf16 weight [n][k] -> LDS padded rows.
// 16B loads + 16B LDS writes, ~bandwidth-floor banks (vs 16-way scalar before).
template <int NT>
static __device__ inline void stage_wbf(bf16_t* Wt, const bf16_t* __restrict__ Wg, int tid) {
    #pragma unroll
    for (int c = tid; c < 2048; c += NT) {
        int n = c >> 4, koff = (c & 15) * 8;
        *reinterpret_cast<bfvec8*>(&Wt[n * LDW + koff]) =
            *reinterpret_cast<const bfvec8*>(&Wg[n * 128 + koff]);
    }
}

// ---------------------------------------------------------------------------
// Init GEMM, swapped operands: D = W^T-frag (A) x X-row-frag (B) = (X@W)^T
// per-tile. MFMA 16x16x32_bf16 layouts (proven): A[m=lane&15][k=quad*8+j],
// B[k][n=lane&15], D reg r -> m=quad*4+r, n=lane&15. With the swap:
// m = output COLUMN, n = output ROW -> lane holds 4 consecutive output cols
// of its own row => 8B vector stores. 512 thr, wave w owns rows w*16..+15.
// ---------------------------------------------------------------------------
__global__ __launch_bounds__(512) void gemm_init(
    const float* __restrict__ X,
    const bf16_t* __restrict__ Wg,     // pre-transposed bf16 [n][k]
    const float* __restrict__ B,
    bf16_t* __restrict__ Y, int M)
{
    __shared__ __align__(16) bf16_t Wt[128 * LDW];
    const int tid = threadIdx.x;
    stage_wbf<512>(Wt, Wg, tid);
    __syncthreads();

    const int wave = tid >> 6, lane = tid & 63;
    const int quad = lane >> 4, ln16 = lane & 15;
    const int row_l = wave * 16 + ln16;
    const int rowg = blockIdx.x * 128 + row_l;
    const int rowc = rowg < M ? rowg : 0;

    // B-fragment: this lane's row of X (fp32 -> bf16 in regs)
    bfvec8 xb[4];
    const float* xp = X + (size_t)rowc * CDIM + quad * 8;
    #pragma unroll
    for (int kc = 0; kc < 4; ++kc) {
        f32x4 lo = *reinterpret_cast<const f32x4*>(xp + kc * 32);
        f32x4 hi = *reinterpret_cast<const f32x4*>(xp + kc * 32 + 4);
        #pragma unroll
        for (int j = 0; j < 4; ++j) {
            xb[kc][j]     = (bf16_t)lo[j];
            xb[kc][j + 4] = (bf16_t)hi[j];
        }
    }

    f32x4 acc[8];
    #pragma unroll
    for (int t = 0; t < 8; ++t) acc[t] = (f32x4){0.f, 0.f, 0.f, 0.f};
    #pragma unroll
    for (int t = 0; t < 8; ++t) {
        const bf16_t* wp = &Wt[(t * 16 + ln16) * LDW + quad * 8];
        #pragma unroll
        for (int kc = 0; kc < 4; ++kc) {
            bfvec8 wv = *reinterpret_cast<const bfvec8*>(wp + kc * 32);
            acc[t] = __builtin_amdgcn_mfma_f32_16x16x32_bf16(wv, xb[kc], acc[t], 0, 0, 0);
        }
    }

    if (rowg < M) {
        #pragma unroll
        for (int t = 0; t < 8; ++t) {
            f32x4 bv = *reinterpret_cast<const f32x4*>(&B[t * 16 + quad * 4]);
            bfvec4 o;
            #pragma unroll
            for (int r = 0; r < 4; ++r) o[r] = (bf16_t)(acc[t][r] + bv[r]);
            *reinterpret_cast<bfvec4*>(&Y[(size_t)rowg * CDIM + t * 16 + quad * 4]) = o;
        }
    }
}

// ---------------------------------------------------------------------------
// CSR build pieces
// ---------------------------------------------------------------------------
__global__ __launch_bounds__(256) void zero_i32(int* __restrict__ p, int n)
{
    int i = blockIdx.x * 256 + threadIdx.x;
    if (i < n) p[i] = 0;
}

// Histogram + rank capture: atomicAdd's return value IS this edge's rank
// within its destination segment. One coalesced 8B store per edge pair.
__global__ __launch_bounds__(256) void hist_rank(
    const int* __restrict__ edge_ui, const int* __restrict__ edge_iu,
    int* __restrict__ deg, int2* __restrict__ rank2)
{
    int i = blockIdx.x * 256 + threadIdx.x;
    if (i >= NEDGE) return;
    int r0 = atomicAdd(&deg[edge_ui[NEDGE + i]], 1);
    int r1 = atomicAdd(&deg[N_ITEM + edge_iu[NEDGE + i]], 1);
    rank2[i] = make_int2(r0, r1);
}

__global__ __launch_bounds__(256) void block_scan(
    int* __restrict__ off, int* __restrict__ bsum, int n)
{
    __shared__ int sh[256];
    int tid = threadIdx.x;
    int i = blockIdx.x * 256 + tid;
    int v = (i < n) ? off[i] : 0;
    sh[tid] = v;
    __syncthreads();
    #pragma unroll
    for (int d = 1; d < 256; d <<= 1) {
        int t = (tid >= d) ? sh[tid - d] : 0;
        __syncthreads();
        sh[tid] += t;
        __syncthreads();
    }
    if (i < n) off[i] = sh[tid] - v;
    if (tid == 255) bsum[blockIdx.x] = sh[255];
}

__global__ __launch_bounds__(1024) void scan_bsums(int* __restrict__ bsum)
{
    __shared__ int sh[1024];
    int tid = threadIdx.x;
    int v = (tid < NB_SCAN) ? bsum[tid] : 0;
    sh[tid] = v;
    __syncthreads();
    #pragma unroll
    for (int d = 1; d < 1024; d <<= 1) {
        int t = (tid >= d) ? sh[tid - d] : 0;
        __syncthreads();
        sh[tid] += t;
        __syncthreads();
    }
    if (tid < NB_SCAN) bsum[tid] = sh[tid] - v;
    if (tid == 1023) bsum[NB_SCAN] = sh[1023];
}

__global__ __launch_bounds__(256) void add_offsets(
    int* __restrict__ off, const int* __restrict__ bsum, int n)
{
    int i = blockIdx.x * 256 + threadIdx.x;
    if (i < n) off[i] += bsum[i >> 8];
    else if (i == n) off[n] = bsum[NB_SCAN];
}

// ---------------------------------------------------------------------------
// Atomic-free, XCD-sliced CSR fill. slot = off[seg] + rank (from hist_rank).
// Block b processes edge-chunk b>>3 and writes only segment-slice b&7; with
// round-robin blockIdx->XCD dispatch all writers of a srcbuf line share one
// XCD's L2 -> write-combining instead of 16 partial-line drains.
// ---------------------------------------------------------------------------
__global__ __launch_bounds__(256) void fill_sliced(
    const int* __restrict__ edge_ui, const int* __restrict__ edge_iu,
    const int* __restrict__ off, const int2* __restrict__ rank2,
    int* __restrict__ srcbuf)
{
    const int r = blockIdx.x & 7;
    const int chunk = blockIdx.x >> 3;
    const int base = chunk * FILL_EPB + threadIdx.x;
    #pragma unroll
    for (int j = 0; j < FILL_EPB / 256; ++j) {
        int i = base + j * 256;
        if (i < NEDGE) {
            int d0 = edge_ui[NEDGE + i];            // item dst; seg = d0
            int d1 = edge_iu[NEDGE + i] + N_ITEM;   // user dst; seg index
            int2 rk = rank2[i];
            if (d0 / SLICE_DIV == r)
                srcbuf[off[d0] + rk.x] = edge_ui[i];
            if (d1 / SLICE_DIV == r)
                srcbuf[off[d1] + rk.y] = edge_iu[i];
        }
    }
}

// ---------------------------------------------------------------------------
// Gather + GIN combine. One node per wave; wave split into 4 groups of 16
// lanes; lane holds bfvec8 (16 B) so 16 lanes cover one 256 B feature row.
// One dwordx4 load instruction serves 4 edges (vs 2 before); unroll 4 keeps
// 16 feature loads in flight per wave against ~600cy L3-hit latency.
// Group g handles edges (e-start) % 4 == g; cross-group reduce = 2 shuffles.
// out = bf16((1+eps)*x + sum F), written by group 0 (16B stores).
// ---------------------------------------------------------------------------
__global__ __launch_bounds__(256) void gather_both(
    const bf16_t* __restrict__ xu, const bf16_t* __restrict__ xi,
    const float* __restrict__ eps2,            // eps + 2*l: [item, user]
    const int* __restrict__ off_all, const int* __restrict__ srcbuf,
    bf16_t* __restrict__ ti, bf16_t* __restrict__ tu)
{
    const int gBI = (N_ITEM + 3) / 4;
    int b = blockIdx.x;
    bool isItem = b < gBI;
    int wave = threadIdx.x >> 6;
    int node = (isItem ? b : b - gBI) * 4 + wave;
    int n = isItem ? N_ITEM : N_USER;
    if (node >= n) return;

    const bfvec8* F = reinterpret_cast<const bfvec8*>(isItem ? xu : xi);
    const bfvec8* X = reinterpret_cast<const bfvec8*>(isItem ? xi : xu);
    const int* off = isItem ? off_all : off_all + N_ITEM;
    bfvec8* out = reinterpret_cast<bfvec8*>(isItem ? ti : tu);
    float s = 1.f + (isItem ? eps2[0] : eps2[1]);

    int lane = threadIdx.x & 63;
    int grp  = lane >> 4;        // 0..3: edge phase
    int l16  = lane & 15;        // 16B chunk within row
    int start = off[node], end = off[node + 1];

    float acc[8];
    #pragma unroll
    for (int j = 0; j < 8; ++j) acc[j] = 0.f;

    int e = start + grp;
    for (; e + 12 < end; e += 16) {
        int s0 = srcbuf[e];
        int s1 = srcbuf[e + 4];
        int s2 = srcbuf[e + 8];
        int s3 = srcbuf[e + 12];
        bfvec8 v0 = F[(size_t)s0 * 16 + l16];
        bfvec8 v1 = F[(size_t)s1 * 16 + l16];
        bfvec8 v2 = F[(size_t)s2 * 16 + l16];
        bfvec8 v3 = F[(size_t)s3 * 16 + l16];
        #pragma unroll
        for (int j = 0; j < 8; ++j)
            acc[j] += ((float)v0[j] + (float)v1[j]) + ((float)v2[j] + (float)v3[j]);
    }
    for (; e + 4 < end; e += 8) {
        int s0 = srcbuf[e];
        int s1 = srcbuf[e + 4];
        bfvec8 v0 = F[(size_t)s0 * 16 + l16];
        bfvec8 v1 = F[(size_t)s1 * 16 + l16];
        #pragma unroll
        for (int j = 0; j < 8; ++j) acc[j] += (float)v0[j] + (float)v1[j];
    }
    for (; e < end; e += 4) {
        bfvec8 v = F[(size_t)srcbuf[e] * 16 + l16];
        #pragma unroll
        for (int j = 0; j < 8; ++j) acc[j] += (float)v[j];
    }

    // cross-group reduce: groups differ only in lane bits 4..5
    #pragma unroll
    for (int j = 0; j < 8; ++j) {
        acc[j] += __shfl_xor(acc[j], 16, 64);
        acc[j] += __shfl_xor(acc[j], 32, 64);
    }

    if (grp == 0) {
        bfvec8 xv = X[(size_t)node * 16 + l16];
        bfvec8 o;
        #pragma unroll
        for (int j = 0; j < 8; ++j) o[j] = (bf16_t)(s * (float)xv[j] + acc[j]);
        out[(size_t)node * 16 + l16] = o;
    }
}

// ---------------------------------------------------------------------------
// Fused MLP (linear->ReLU x2) + LayerNorm + ReLU, both node types, swapped
// MFMA operands: lane holds 4 consecutive OUTPUT COLS of its own row ->
// At round-trip and global stores are vector writes; LN needs only 2 quad
// shuffles. 512 thr (8 waves x 16 rows), weights pre-transposed bf16.
// LDS 69,632 B -> 2 blocks/CU -> 4 waves/SIMD.
// ---------------------------------------------------------------------------
__global__ __launch_bounds__(512) void mlp_ln_both(
    const bf16_t* __restrict__ ti, const bf16_t* __restrict__ tu,
    const bf16_t* __restrict__ wg,    // this layer: [itemW1, itemW2, userW1, userW2], bf16 [n][k]
    const float* __restrict__ mlpb,   // mlp_b + l*4*128
    const float* __restrict__ lng,    // ln_g + l*2*128
    const float* __restrict__ lnb,    // ln_b + l*2*128
    bf16_t* __restrict__ xib, bf16_t* __restrict__ xub,   // bf16 outs (l=0)
    float* __restrict__ xif, float* __restrict__ xuf,     // fp32 outs (l=1)
    int f32out)
{
    __shared__ __align__(16) bf16_t Wt[128 * LDW];
    __shared__ __align__(16) bf16_t At[128 * LDW];

    const int gBI = (N_ITEM + 127) / 128;
    int b = blockIdx.x;
    bool isItem = b < gBI;
    const bf16_t* X = isItem ? ti : tu;
    bf16_t* Yb      = isItem ? xib : xub;
    float*  Yf      = isItem ? xif : xuf;
    int M  = isItem ? N_ITEM : N_USER;
    int bx = isItem ? b : b - gBI;
    // edge type 0 = (user->item) => item dst; 1 = (item->user) => user dst
    const bf16_t* W1 = wg + (isItem ? 0 : 2) * 16384;
    const bf16_t* W2 = W1 + 16384;
    const float* B1 = mlpb + (isItem ? 0 : 2) * 128;
    const float* B2 = B1 + 128;
    // node type 0 = user, 1 = item
    const float* G  = lng + (isItem ? 128 : 0);
    const float* Bb = lnb + (isItem ? 128 : 0);

    const int tid = threadIdx.x;
    stage_wbf<512>(Wt, W1, tid);
    __syncthreads();

    const int wave = tid >> 6, lane = tid & 63;
    const int quad = lane >> 4, ln16 = lane & 15;
    const int row_l = wave * 16 + ln16;
    const int rowg = bx * 128 + row_l;
    const int rowc = rowg < M ? rowg : 0;

    // ---- GEMM1: relu(X@W1+b1) -> At[row][k] (vector 8B writes) ----
    bfvec8 xb[4];
    const bf16_t* xp = X + (size_t)rowc * CDIM + quad * 8;
    #pragma unroll
    for (int kc = 0; kc < 4; ++kc)
        xb[kc] = *reinterpret_cast<const bfvec8*>(xp + kc * 32);

    f32x4 acc[8];
    #pragma unroll
    for (int t = 0; t < 8; ++t) acc[t] = (f32x4){0.f, 0.f, 0.f, 0.f};
    #pragma unroll
    for (int t = 0; t < 8; ++t) {
        const bf16_t* wp = &Wt[(t * 16 + ln16) * LDW + quad * 8];
        #pragma unroll
        for (int kc = 0; kc < 4; ++kc) {
            bfvec8 wv = *reinterpret_cast<const bfvec8*>(wp + kc * 32);
            acc[t] = __builtin_amdgcn_mfma_f32_16x16x32_bf16(wv, xb[kc], acc[t], 0, 0, 0);
        }
    }

    #pragma unroll
    for (int t = 0; t < 8; ++t) {
        f32x4 bv = *reinterpret_cast<const f32x4*>(&B1[t * 16 + quad * 4]);
        bfvec4 o;
        #pragma unroll
        for (int r = 0; r < 4; ++r) {
            float v = acc[t][r] + bv[r];
            o[r] = (bf16_t)(v > 0.f ? v : 0.f);
        }
        *reinterpret_cast<bfvec4*>(&At[row_l * LDW + t * 16 + quad * 4]) = o;
    }
    __syncthreads();
    stage_wbf<512>(Wt, W2, tid);       // overwrite W1; all GEMM1 reads complete
    __syncthreads();

    // ---- GEMM2 from At + bias + ReLU + LayerNorm + ReLU -> Y ----
    bfvec8 hb[4];
    #pragma unroll
    for (int kc = 0; kc < 4; ++kc)
        hb[kc] = *reinterpret_cast<const bfvec8*>(&At[row_l * LDW + kc * 32 + quad * 8]);

    #pragma unroll
    for (int t = 0; t < 8; ++t) acc[t] = (f32x4){0.f, 0.f, 0.f, 0.f};
    #pragma unroll
    for (int t = 0; t < 8; ++t) {
        const bf16_t* wp = &Wt[(t * 16 + ln16) * LDW + quad * 8];
        #pragma unroll
        for (int kc = 0; kc < 4; ++kc) {
            bfvec8 wv = *reinterpret_cast<const bfvec8*>(wp + kc * 32);
            acc[t] = __builtin_amdgcn_mfma_f32_16x16x32_bf16(wv, hb[kc], acc[t], 0, 0, 0);
        }
    }

    #pragma unroll
    for (int t = 0; t < 8; ++t) {
        f32x4 bv = *reinterpret_cast<const f32x4*>(&B2[t * 16 + quad * 4]);
        #pragma unroll
        for (int r = 0; r < 4; ++r) {
            float v = acc[t][r] + bv[r];
            acc[t][r] = v > 0.f ? v : 0.f;     // ReLU after 2nd linear
        }
    }

    // LN over this lane's own row: 32 in-lane values + 2 quad shuffles
    float sm = 0.f;
    #pragma unroll
    for (int t = 0; t < 8; ++t)
        #pragma unroll
        for (int r = 0; r < 4; ++r) sm += acc[t][r];
    sm += __shfl_xor(sm, 16, 64);
    sm += __shfl_xor(sm, 32, 64);
    float mean = sm * (1.f / 128.f);
    float sq = 0.f;
    #pragma unroll
    for (int t = 0; t < 8; ++t)
        #pragma unroll
        for (int r = 0; r < 4; ++r) { float d = acc[t][r] - mean; sq += d * d; }
    sq += __shfl_xor(sq, 16, 64);
    sq += __shfl_xor(sq, 32, 64);
    float rs = rsqrtf(sq * (1.f / 128.f) + 1e-5f);

    if (rowg < M) {
        if (f32out) {
            #pragma unroll
            for (int t = 0; t < 8; ++t) {
                f32x4 g4 = *reinterpret_cast<const f32x4*>(&G[t * 16 + quad * 4]);
                f32x4 b4 = *reinterpret_cast<const f32x4*>(&Bb[t * 16 + quad * 4]);
                f32x4 y;
                #pragma unroll
                for (int r = 0; r < 4; ++r) {
                    float v = (acc[t][r] - mean) * rs * g4[r] + b4[r];
                    y[r] = v > 0.f ? v : 0.f;
                }
                *reinterpret_cast<f32x4*>(&Yf[(size_t)rowg * CDIM + t * 16 + quad * 4]) = y;
            }
        } else {
            #pragma unroll
            for (int t = 0; t < 8; ++t) {
                f32x4 g4 = *reinterpret_cast<const f32x4*>(&G[t * 16 + quad * 4]);
                f32x4 b4 = *reinterpret_cast<const f32x4*>(&Bb[t * 16 + quad * 4]);
                bfvec4 y;
                #pragma unroll
                for (int r = 0; r < 4; ++r) {
                    float v = (acc[t][r] - mean) * rs * g4[r] + b4[r];
                    y[r] = (bf16_t)(v > 0.f ? v : 0.f);
                }
                *reinterpret_cast<bfvec4*>(&Yb[(size_t)rowg * CDIM + t * 16 + quad * 4]) = y;
            }
        }
    }
}

// ---------------------------------------------------------------------------
extern "C" void kernel_launch(void* const* d_in, const int* in_sizes, int n_in,
                              void* d_out, int out_size, void* d_ws, size_t ws_size,
                              hipStream_t stream)
{
    const float* x_user = (const float*)d_in[0];
    const float* x_item = (const float*)d_in[1];
    const float* W_init = (const float*)d_in[2];
    const float* b_init = (const float*)d_in[3];
    const float* mlp_W  = (const float*)d_in[4];
    const float* mlp_b  = (const float*)d_in[5];
    const float* eps    = (const float*)d_in[6];
    const float* ln_g   = (const float*)d_in[7];
    const float* ln_b   = (const float*)d_in[8];
    const int* edge_ui  = (const int*)d_in[9];
    const int* edge_iu  = (const int*)d_in[10];

    // final fp32 outputs
    float* xuf = (float*)d_out;                     // [N_USER,128]
    float* xif = xuf + (size_t)N_USER * CDIM;       // [N_ITEM,128]

    // ws: bf16 activations + CSR + pre-transposed weights
    char* w = (char*)d_ws;
    bf16_t* xub = (bf16_t*)w;                                  // 25.6 MB
    bf16_t* xib = xub + (size_t)N_USER * CDIM;                 // 12.8 MB
    bf16_t* tub = xib + (size_t)N_ITEM * CDIM;                 // 25.6 MB
    bf16_t* tib = tub + (size_t)N_USER * CDIM;                 // 12.8 MB
    int* off_all = (int*)(tib + (size_t)N_ITEM * CDIM);        // N_SEG+1
    int* bsum    = off_all + (N_SEG + 4);
    int* srcbuf  = bsum + (NB_SCAN + 2);                       // 2*NEDGE
    bf16_t* wtg  = (bf16_t*)(srcbuf + 2 * NEDGE);              // 10*16384 bf16 (16B-aligned)

    // rank2 aliases tub: live only hist_rank -> fill_sliced, before any
    // gather_both writes tub. 4.8 MB < 25.6 MB region. 8B-aligned.
    int2* rank2 = (int2*)tub;

    const int gU = (N_USER + 127) / 128;            // 782
    const int gI = (N_ITEM + 127) / 128;            // 391
    const int gSeg = (N_SEG + 256) / 256;
    const int gE = (NEDGE + 255) / 256;             // 2344
    const int gGather = (N_ITEM + 3) / 4 + (N_USER + 3) / 4;

    // one-time weight transpose (needs only inputs)
    prep_weights<<<640, 256, 0, stream>>>(W_init, mlp_W, wtg);

    // CSR prep
    zero_i32<<<(N_SEG + 255) / 256, 256, 0, stream>>>(off_all, N_SEG);
    hist_rank<<<gE, 256, 0, stream>>>(edge_ui, edge_iu, off_all, rank2);
    block_scan<<<NB_SCAN, 256, 0, stream>>>(off_all, bsum, N_SEG);
    scan_bsums<<<1, 1024, 0, stream>>>(bsum);
    add_offsets<<<gSeg, 256, 0, stream>>>(off_all, bsum, N_SEG);
    fill_sliced<<<FILL_NCHUNK * 8, 256, 0, stream>>>(edge_ui, edge_iu, off_all, rank2, srcbuf);

    // initial projection -> bf16 ws
    gemm_init<<<gU, 512, 0, stream>>>(x_user, wtg,         b_init,       xub, N_USER);
    gemm_init<<<gI, 512, 0, stream>>>(x_item, wtg + 16384, b_init + 128, xib, N_ITEM);

    for (int l = 0; l < 2; ++l) {
        gather_both<<<gGather, 256, 0, stream>>>(
            xub, xib, eps + 2 * l, off_all, srcbuf, tib, tub);
        mlp_ln_both<<<gI + gU, 512, 0, stream>>>(
            tib, tub, wtg + (size_t)(2 + l * 4) * 16384, mlp_b + l * 4 * 128,
            ln_g + l * 2 * 128, ln_b + l * 2 * 128,
            xib, xub, xif, xuf, (l == 1) ? 1 : 0);
    }
}